// Round 12
// baseline (190.643 us; speedup 1.0000x reference)
//
#include <hip/hip_runtime.h>
#include <hip/hip_bf16.h>

#define TWO_N 8192
#define NHALF 4096
#define D 256
#define NTILE 64            // 8192 / 128 tiles per dimension
#define NTRI  2080          // NTILE*(NTILE+1)/2 live triangle tiles
#define BLK_ELEMS 32768     // 32 kchunks * 128 rows * 8 elems per 128-row block
static constexpr float INV_T = 2.0f; // 1 / 0.5

typedef __attribute__((ext_vector_type(8))) short short8;
typedef __attribute__((ext_vector_type(4))) float f32x4;

#define AS1 __attribute__((address_space(1)))
#define AS3 __attribute__((address_space(3)))

__device__ __forceinline__ ushort f2bfu(float f) {
    __hip_bfloat16 b = __float2bfloat16(f);
    return *reinterpret_cast<ushort*>(&b);
}

// ------ kernel 1: fused normalize + positive-pair sim, blocked-K-major out --
// znb layout: [rowblock(64)][kchunk(32)][row-in-block(128)][elem(8)]
__global__ __launch_bounds__(256) void norm_pos_kernel(
        const float* __restrict__ z_i, const float* __restrict__ z_j,
        ushort* __restrict__ znb, float* __restrict__ sim_pos,
        float* __restrict__ denom) {
    const int wid = threadIdx.x >> 6, lane = threadIdx.x & 63;
    const int i = blockIdx.x * 4 + wid;  // 0..4095
    const float4 vi = *reinterpret_cast<const float4*>(z_i + (size_t)i * D + lane * 4);
    const float4 vj = *reinterpret_cast<const float4*>(z_j + (size_t)i * D + lane * 4);
    float ssi = vi.x * vi.x + vi.y * vi.y + vi.z * vi.z + vi.w * vi.w;
    float ssj = vj.x * vj.x + vj.y * vj.y + vj.z * vj.z + vj.w * vj.w;
    float dt  = vi.x * vj.x + vi.y * vj.y + vi.z * vj.z + vi.w * vj.w;
    #pragma unroll
    for (int off = 32; off; off >>= 1) {
        ssi += __shfl_xor(ssi, off);
        ssj += __shfl_xor(ssj, off);
        dt  += __shfl_xor(dt,  off);
    }
    const float ri = rsqrtf(ssi), rj = rsqrtf(ssj);
    ushort4 oi, oj;
    oi.x = f2bfu(vi.x * ri); oi.y = f2bfu(vi.y * ri);
    oi.z = f2bfu(vi.z * ri); oi.w = f2bfu(vi.w * ri);
    oj.x = f2bfu(vj.x * rj); oj.y = f2bfu(vj.y * rj);
    oj.z = f2bfu(vj.z * rj); oj.w = f2bfu(vj.w * rj);
    const int c = lane >> 1, e = (lane & 1) * 4;
    const int i2 = i + NHALF;
    const size_t bi = ((size_t)(i  >> 7) * 32 + c) * 1024 + (i  & 127) * 8 + e;
    const size_t bj = ((size_t)(i2 >> 7) * 32 + c) * 1024 + (i2 & 127) * 8 + e;
    *reinterpret_cast<ushort4*>(znb + bi) = oi;
    *reinterpret_cast<ushort4*>(znb + bj) = oj;
    if (lane == 0) {
        const float sp = dt * ri * rj * INV_T;
        sim_pos[i] = sp;
        sim_pos[i + NHALF] = sp;   // symmetric
        denom[i] = 0.0f;
        denom[i + NHALF] = 0.0f;
    }
}

// ======== shared GEMM pieces (R7-exact geometry & schedule) ========
#define GEMM_SETUP                                                              \
    const int tid  = threadIdx.x;                                               \
    const int lane = tid & 63;                                                  \
    const int wid  = tid >> 6;                                                  \
    const int wr   = wid >> 1;                                                  \
    const int wc   = wid & 1;                                                   \
    const int r16  = lane & 15;                                                 \
    const int kgrp = lane >> 4;                                                 \
    const int row0 = tr * 128;                                                  \
    const int col0 = tc * 128;                                                  \
    const ushort* gA = znb + (size_t)tr * BLK_ELEMS + tid * 8;                  \
    const ushort* gB = znb + (size_t)tc * BLK_ELEMS + tid * 8;                  \
    const int d0 = (0 * 256 + wid * 64) * 8;                                    \
    const int d1 = (1 * 256 + wid * 64) * 8;

#define STAGE(buf, koff)                                                        \
    do {                                                                        \
        __builtin_amdgcn_global_load_lds((const AS1 void*)(gA + (koff)),        \
            (AS3 void*)(As[buf] + d0), 16, 0, 0);                               \
        __builtin_amdgcn_global_load_lds((const AS1 void*)(gA + (koff) + 2048), \
            (AS3 void*)(As[buf] + d1), 16, 0, 0);                               \
        __builtin_amdgcn_global_load_lds((const AS1 void*)(gB + (koff)),        \
            (AS3 void*)(Bs[buf] + d0), 16, 0, 0);                               \
        __builtin_amdgcn_global_load_lds((const AS1 void*)(gB + (koff) + 2048), \
            (AS3 void*)(Bs[buf] + d1), 16, 0, 0);                               \
    } while (0)

// ------ kernel 2 (PRODUCTION): byte-identical to R7 (43 us measured) --------
__global__ __launch_bounds__(256) void gemm_denom_kernel(
        const ushort* __restrict__ znb, float* __restrict__ denom) {
    const int tr = blockIdx.x;
    const int tc = blockIdx.y;
    if (tc < tr) return;  // block-uniform exit before any sync

    __shared__ ushort As[3][4 * 128 * 8];  // 3 x 8 KB
    __shared__ ushort Bs[3][4 * 128 * 8];

    GEMM_SETUP

    f32x4 acc[4][4];
    #pragma unroll
    for (int m = 0; m < 4; ++m)
        #pragma unroll
        for (int n = 0; n < 4; ++n) {
            f32x4 z = {0.f, 0.f, 0.f, 0.f};
            acc[m][n] = z;
        }

    STAGE(0, 0);
    STAGE(1, 4096);

    #pragma unroll
    for (int ks = 0; ks < 8; ++ks) {
        const int cur = ks % 3;
        if (ks < 7) asm volatile("s_waitcnt vmcnt(4)" ::: "memory");
        else        asm volatile("s_waitcnt vmcnt(0)" ::: "memory");
        __builtin_amdgcn_s_barrier();
        asm volatile("" ::: "memory");
        if (ks < 6) STAGE((ks + 2) % 3, (ks + 2) * 4096);
        short8 a[4], b[4];
        #pragma unroll
        for (int m = 0; m < 4; ++m)
            a[m] = *reinterpret_cast<const short8*>(
                As[cur] + ((kgrp * 128) + wr * 64 + m * 16 + r16) * 8);
        #pragma unroll
        for (int n = 0; n < 4; ++n)
            b[n] = *reinterpret_cast<const short8*>(
                Bs[cur] + ((kgrp * 128) + wc * 64 + n * 16 + r16) * 8);
        #pragma unroll
        for (int m = 0; m < 4; ++m)
            #pragma unroll
            for (int n = 0; n < 4; ++n)
                acc[m][n] = __builtin_amdgcn_mfma_f32_16x16x32_bf16(
                    a[m], b[n], acc[m][n], 0, 0, 0);
    }

    const bool offdiag = (tr != tc);
    float cs[4] = {0.f, 0.f, 0.f, 0.f};
    #pragma unroll
    for (int m = 0; m < 4; ++m) {
        #pragma unroll
        for (int reg = 0; reg < 4; ++reg) {
            const int rg = row0 + wr * 64 + m * 16 + kgrp * 4 + reg;
            float rs = 0.f;
            #pragma unroll
            for (int n = 0; n < 4; ++n) {
                const int cg = col0 + wc * 64 + n * 16 + r16;
                float e = __expf(acc[m][n][reg] * INV_T);
                if (rg == cg) e = 0.f;
                rs += e;
                cs[n] += e;
            }
            rs += __shfl_xor(rs, 1);
            rs += __shfl_xor(rs, 2);
            rs += __shfl_xor(rs, 4);
            rs += __shfl_xor(rs, 8);
            if (r16 == 0) atomicAdd(&denom[rg], rs);
        }
    }
    if (offdiag) {
        #pragma unroll
        for (int n = 0; n < 4; ++n) {
            cs[n] += __shfl_xor(cs[n], 16);
            cs[n] += __shfl_xor(cs[n], 32);
        }
        if (kgrp == 0) {
            #pragma unroll
            for (int n = 0; n < 4; ++n)
                atomicAdd(&denom[col0 + wc * 64 + n * 16 + r16], cs[n]);
        }
    }
}

// ------ ablation probes, 4x-repeated K-loop (32 ring steps), full 2080 grid --
// MODE 0: staging ring + counted vmcnt + barriers only (LDS never read)
// MODE 1: + ds_read_b128 (kept live via asm, no MFMA)
// MODE 2: + MFMA (acc folded to sink)
// Each probe runs ~4x the steady-state phase cost of production -> appears in
// top-5; phase cost = probe/4. Writes only to sink scratch.
template<int MODE>
__global__ __launch_bounds__(256) void gemm_probe(
        const ushort* __restrict__ znb, float* __restrict__ sink) {
    int rem = blockIdx.x;
    int tr = 0;
    while (rem >= NTILE - tr) { rem -= NTILE - tr; ++tr; }
    const int tc = tr + rem;

    __shared__ ushort As[3][4 * 128 * 8];
    __shared__ ushort Bs[3][4 * 128 * 8];

    GEMM_SETUP

    f32x4 acc[4][4];
    #pragma unroll
    for (int m = 0; m < 4; ++m)
        #pragma unroll
        for (int n = 0; n < 4; ++n) {
            f32x4 z = {0.f, 0.f, 0.f, 0.f};
            acc[m][n] = z;
        }

    STAGE(0, 0);
    STAGE(1, 4096);

    #pragma unroll
    for (int step = 0; step < 32; ++step) {
        const int cur = step % 3;
        if (step < 31) asm volatile("s_waitcnt vmcnt(4)" ::: "memory");
        else           asm volatile("s_waitcnt vmcnt(0)" ::: "memory");
        __builtin_amdgcn_s_barrier();
        asm volatile("" ::: "memory");
        if (step < 30) STAGE((step + 2) % 3, ((step + 2) & 7) * 4096);
        if constexpr (MODE >= 1) {
            short8 a[4], b[4];
            #pragma unroll
            for (int m = 0; m < 4; ++m)
                a[m] = *reinterpret_cast<const short8*>(
                    As[cur] + ((kgrp * 128) + wr * 64 + m * 16 + r16) * 8);
            #pragma unroll
            for (int n = 0; n < 4; ++n)
                b[n] = *reinterpret_cast<const short8*>(
                    Bs[cur] + ((kgrp * 128) + wc * 64 + n * 16 + r16) * 8);
            if constexpr (MODE == 1) {
                // keep ds_reads live without consuming them (rule #17)
                #pragma unroll
                for (int m = 0; m < 4; ++m) asm volatile("" :: "v"(a[m]));
                #pragma unroll
                for (int n = 0; n < 4; ++n) asm volatile("" :: "v"(b[n]));
            } else {
                #pragma unroll
                for (int m = 0; m < 4; ++m)
                    #pragma unroll
                    for (int n = 0; n < 4; ++n)
                        acc[m][n] = __builtin_amdgcn_mfma_f32_16x16x32_bf16(
                            a[m], b[n], acc[m][n], 0, 0, 0);
            }
        }
    }

    if constexpr (MODE == 2) {
        float f = 0.f;
        #pragma unroll
        for (int m = 0; m < 4; ++m)
            #pragma unroll
            for (int n = 0; n < 4; ++n)
                f += acc[m][n][0] + acc[m][n][1] + acc[m][n][2] + acc[m][n][3];
        #pragma unroll
        for (int off = 32; off; off >>= 1) f += __shfl_xor(f, off);
        if (lane == 0) atomicAdd(&sink[blockIdx.x & 255], f);
    } else {
        if (tid == 0) atomicAdd(&sink[blockIdx.x & 255], 1.0f);
    }
}

// ---------------- kernel 3: final loss reduction ----------------
__global__ __launch_bounds__(1024) void final_kernel(
        const float* __restrict__ sim_pos, const float* __restrict__ denom,
        float* __restrict__ out) {
    const int tid = threadIdx.x;
    float s = 0.f;
    for (int i = tid; i < TWO_N; i += 1024)
        s += sim_pos[i] - logf(denom[i]);
    #pragma unroll
    for (int off = 32; off; off >>= 1) s += __shfl_down(s, off);
    __shared__ float red[16];
    const int wid = tid >> 6, lane = tid & 63;
    if (lane == 0) red[wid] = s;
    __syncthreads();
    if (tid == 0) {
        float t = 0.f;
        #pragma unroll
        for (int w = 0; w < 16; ++w) t += red[w];
        out[0] = -t / (float)TWO_N;
    }
}

extern "C" void kernel_launch(void* const* d_in, const int* in_sizes, int n_in,
                              void* d_out, int out_size, void* d_ws, size_t ws_size,
                              hipStream_t stream) {
    const float* z_i = (const float*)d_in[0];
    const float* z_j = (const float*)d_in[1];
    float* out = (float*)d_out;

    ushort* znb      = (ushort*)d_ws;                                  // 4 MB
    float*  sim_pos  = (float*)((char*)d_ws + (size_t)TWO_N * D * 2);  // 32 KB
    float*  denom    = sim_pos + TWO_N;                                // 32 KB
    float*  sink     = denom + TWO_N;                                  // 1 KB probe sink

    norm_pos_kernel<<<NHALF / 4, 256, 0, stream>>>(z_i, z_j, znb, sim_pos, denom);
    dim3 grid(NTILE, NTILE);
    gemm_denom_kernel<<<grid, 256, 0, stream>>>(znb, denom);
    final_kernel<<<1, 1024, 0, stream>>>(sim_pos, denom, out);

    // ---- full-scale, 4x-repeated ablation probes (write only to sink) ----
    gemm_probe<0><<<NTRI, 256, 0, stream>>>(znb, sink);
    gemm_probe<1><<<NTRI, 256, 0, stream>>>(znb, sink);
    gemm_probe<2><<<NTRI, 256, 0, stream>>>(znb, sink);
}

// Round 13
// 78.172 us; speedup vs baseline: 2.4388x; 2.4388x over previous
//
#include <hip/hip_runtime.h>
#include <hip/hip_bf16.h>

#define TWO_N 8192
#define NHALF 4096
#define D 256
#define NTILE 64            // 8192 / 128 tiles per dimension
#define NTRI  2080          // NTILE*(NTILE+1)/2 live triangle tiles
#define NPERS 768           // persistent blocks = 3 per CU exactly
#define BLK_ELEMS 32768     // 32 kchunks * 128 rows * 8 elems per 128-row block
static constexpr float INV_T = 2.0f; // 1 / 0.5

typedef __attribute__((ext_vector_type(8))) short short8;
typedef __attribute__((ext_vector_type(4))) float f32x4;

#define AS1 __attribute__((address_space(1)))
#define AS3 __attribute__((address_space(3)))

__device__ __forceinline__ ushort f2bfu(float f) {
    __hip_bfloat16 b = __float2bfloat16(f);
    return *reinterpret_cast<ushort*>(&b);
}

// ------ kernel 1: fused normalize + positive-pair sim, blocked-K-major out --
// znb layout: [rowblock(64)][kchunk(32)][row-in-block(128)][elem(8)]
__global__ __launch_bounds__(256) void norm_pos_kernel(
        const float* __restrict__ z_i, const float* __restrict__ z_j,
        ushort* __restrict__ znb, float* __restrict__ sim_pos,
        float* __restrict__ denom) {
    const int wid = threadIdx.x >> 6, lane = threadIdx.x & 63;
    const int i = blockIdx.x * 4 + wid;  // 0..4095
    const float4 vi = *reinterpret_cast<const float4*>(z_i + (size_t)i * D + lane * 4);
    const float4 vj = *reinterpret_cast<const float4*>(z_j + (size_t)i * D + lane * 4);
    float ssi = vi.x * vi.x + vi.y * vi.y + vi.z * vi.z + vi.w * vi.w;
    float ssj = vj.x * vj.x + vj.y * vj.y + vj.z * vj.z + vj.w * vj.w;
    float dt  = vi.x * vj.x + vi.y * vj.y + vi.z * vj.z + vi.w * vj.w;
    #pragma unroll
    for (int off = 32; off; off >>= 1) {
        ssi += __shfl_xor(ssi, off);
        ssj += __shfl_xor(ssj, off);
        dt  += __shfl_xor(dt,  off);
    }
    const float ri = rsqrtf(ssi), rj = rsqrtf(ssj);
    ushort4 oi, oj;
    oi.x = f2bfu(vi.x * ri); oi.y = f2bfu(vi.y * ri);
    oi.z = f2bfu(vi.z * ri); oi.w = f2bfu(vi.w * ri);
    oj.x = f2bfu(vj.x * rj); oj.y = f2bfu(vj.y * rj);
    oj.z = f2bfu(vj.z * rj); oj.w = f2bfu(vj.w * rj);
    const int c = lane >> 1, e = (lane & 1) * 4;
    const int i2 = i + NHALF;
    const size_t bi = ((size_t)(i  >> 7) * 32 + c) * 1024 + (i  & 127) * 8 + e;
    const size_t bj = ((size_t)(i2 >> 7) * 32 + c) * 1024 + (i2 & 127) * 8 + e;
    *reinterpret_cast<ushort4*>(znb + bi) = oi;
    *reinterpret_cast<ushort4*>(znb + bj) = oj;
    if (lane == 0) {
        const float sp = dt * ri * rj * INV_T;
        sim_pos[i] = sp;
        sim_pos[i + NHALF] = sp;   // symmetric
        denom[i] = 0.0f;
        denom[i + NHALF] = 0.0f;
    }
}

// ------ kernel 2: PERSISTENT ring GEMM + exp + row/col sums ------
// 768 blocks (3/CU exactly, one dispatch wave). Block b processes tiles
// {b, b+768, b+1536} of the compact upper triangle. The ring-3 counted-vmcnt
// pipeline (R7, proven) runs CONTINUOUSLY across tiles: steps 6,7 of tile T
// stage tile T+1's slices 0,1; the epilogue then runs while those stages fly.
// After the epilogue's atomics: one vmcnt(0) drain (atomics pollute the vm
// counter; next tile's stages have already landed during the epilogue).
__global__ __launch_bounds__(256) void gemm_denom_kernel(
        const ushort* __restrict__ znb, float* __restrict__ denom) {
    __shared__ ushort As[3][4 * 128 * 8];  // 3 x 8 KB
    __shared__ ushort Bs[3][4 * 128 * 8];

    const int tid  = threadIdx.x;
    const int lane = tid & 63;
    const int wid  = tid >> 6;
    const int wr   = wid >> 1;
    const int wc   = wid & 1;
    const int r16  = lane & 15;
    const int kgrp = lane >> 4;
    const int d0 = (0 * 256 + wid * 64) * 8;   // wave-uniform LDS dests
    const int d1 = (1 * 256 + wid * 64) * 8;

    // decode first tile (triangle row-major)
    int tr = 0, rem = (int)blockIdx.x;
    while (rem >= NTILE - tr) { rem -= NTILE - tr; ++tr; }
    int tc = tr + rem;

    const ushort* gA = znb + (size_t)tr * BLK_ELEMS + tid * 8;
    const ushort* gB = znb + (size_t)tc * BLK_ELEMS + tid * 8;

    #define STG(buf, pA, pB, koff)                                                \
        do {                                                                      \
            __builtin_amdgcn_global_load_lds((const AS1 void*)((pA) + (koff)),    \
                (AS3 void*)(As[buf] + d0), 16, 0, 0);                             \
            __builtin_amdgcn_global_load_lds((const AS1 void*)((pA) + (koff) + 2048), \
                (AS3 void*)(As[buf] + d1), 16, 0, 0);                             \
            __builtin_amdgcn_global_load_lds((const AS1 void*)((pB) + (koff)),    \
                (AS3 void*)(Bs[buf] + d0), 16, 0, 0);                             \
            __builtin_amdgcn_global_load_lds((const AS1 void*)((pB) + (koff) + 2048), \
                (AS3 void*)(Bs[buf] + d1), 16, 0, 0);                             \
        } while (0)

    // prologue: first tile's slices 0,1 (8 loads/thread in flight)
    STG(0, gA, gB, 0);
    STG(1, gA, gB, 4096);
    int ph = 0;  // ring phase: tile-local buf = (ph + ks) % 3

    for (int tile = (int)blockIdx.x; tile < NTRI; tile += NPERS) {
        const bool hasNext = (tile + NPERS) < NTRI;
        int tr2 = tr, tc2 = tc;
        const ushort *gA2 = gA, *gB2 = gB;
        if (hasNext) {
            int r2 = tile + NPERS;
            tr2 = 0;
            while (r2 >= NTILE - tr2) { r2 -= NTILE - tr2; ++tr2; }
            tc2 = tr2 + r2;
            gA2 = znb + (size_t)tr2 * BLK_ELEMS + tid * 8;
            gB2 = znb + (size_t)tc2 * BLK_ELEMS + tid * 8;
        }
        const int row0 = tr * 128;
        const int col0 = tc * 128;

        f32x4 acc[4][4];
        #pragma unroll
        for (int m = 0; m < 4; ++m)
            #pragma unroll
            for (int n = 0; n < 4; ++n) {
                f32x4 z = {0.f, 0.f, 0.f, 0.f};
                acc[m][n] = z;
            }

        #pragma unroll
        for (int ks = 0; ks < 8; ++ks) {
            const int cur  = (ph + ks) % 3;
            const int nbuf = (ph + ks + 2) % 3;
            // counted wait: stage(ks) landed; stage(ks+1) stays in flight
            if (ks == 7 && !hasNext) asm volatile("s_waitcnt vmcnt(0)" ::: "memory");
            else                     asm volatile("s_waitcnt vmcnt(4)" ::: "memory");
            __builtin_amdgcn_s_barrier();
            asm volatile("" ::: "memory");  // pin: no loads migrate above barrier
            if (ks < 6)       STG(nbuf, gA,  gB,  (ks + 2) * 4096);
            else if (hasNext) STG(nbuf, gA2, gB2, (ks - 6) * 4096);
            short8 a[4], b[4];
            #pragma unroll
            for (int m = 0; m < 4; ++m)
                a[m] = *reinterpret_cast<const short8*>(
                    As[cur] + ((kgrp * 128) + wr * 64 + m * 16 + r16) * 8);
            #pragma unroll
            for (int n = 0; n < 4; ++n)
                b[n] = *reinterpret_cast<const short8*>(
                    Bs[cur] + ((kgrp * 128) + wc * 64 + n * 16 + r16) * 8);
            #pragma unroll
            for (int m = 0; m < 4; ++m)
                #pragma unroll
                for (int n = 0; n < 4; ++n)
                    acc[m][n] = __builtin_amdgcn_mfma_f32_16x16x32_bf16(
                        a[m], b[n], acc[m][n], 0, 0, 0);
        }
        ph = (ph + 2) % 3;  // 8 steps advance the ring phase by 8 % 3 = 2

        // ---- epilogue (runs while next tile's stages are in flight) ----
        const bool offdiag = (tr != tc);
        float cs[4] = {0.f, 0.f, 0.f, 0.f};
        #pragma unroll
        for (int m = 0; m < 4; ++m) {
            #pragma unroll
            for (int reg = 0; reg < 4; ++reg) {
                const int rg = row0 + wr * 64 + m * 16 + kgrp * 4 + reg;
                float rs = 0.f;
                #pragma unroll
                for (int n = 0; n < 4; ++n) {
                    const int cg = col0 + wc * 64 + n * 16 + r16;
                    float e = __expf(acc[m][n][reg] * INV_T);
                    if (rg == cg) e = 0.f;   // only possible when tr==tc
                    rs += e;
                    cs[n] += e;
                }
                rs += __shfl_xor(rs, 1);
                rs += __shfl_xor(rs, 2);
                rs += __shfl_xor(rs, 4);
                rs += __shfl_xor(rs, 8);
                if (r16 == 0) atomicAdd(&denom[rg], rs);
            }
        }
        if (offdiag) {
            #pragma unroll
            for (int n = 0; n < 4; ++n) {
                cs[n] += __shfl_xor(cs[n], 16);
                cs[n] += __shfl_xor(cs[n], 32);
            }
            if (kgrp == 0) {
                #pragma unroll
                for (int n = 0; n < 4; ++n)
                    atomicAdd(&denom[col0 + wc * 64 + n * 16 + r16], cs[n]);
            }
        }

        if (hasNext) {
            // drain epilogue atomics from the vm counter so the next tile's
            // counted vmcnt(4) gates see only stage loads. The next tile's
            // slices 0,1 landed during the epilogue -> this wait is ~free.
            asm volatile("s_waitcnt vmcnt(0)" ::: "memory");
        }
        tr = tr2; tc = tc2; gA = gA2; gB = gB2;
    }
    #undef STG
}

// ---------------- kernel 3: final loss reduction ----------------
__global__ __launch_bounds__(1024) void final_kernel(
        const float* __restrict__ sim_pos, const float* __restrict__ denom,
        float* __restrict__ out) {
    const int tid = threadIdx.x;
    float s = 0.f;
    for (int i = tid; i < TWO_N; i += 1024)
        s += sim_pos[i] - logf(denom[i]);
    #pragma unroll
    for (int off = 32; off; off >>= 1) s += __shfl_down(s, off);
    __shared__ float red[16];
    const int wid = tid >> 6, lane = tid & 63;
    if (lane == 0) red[wid] = s;
    __syncthreads();
    if (tid == 0) {
        float t = 0.f;
        #pragma unroll
        for (int w = 0; w < 16; ++w) t += red[w];
        out[0] = -t / (float)TWO_N;
    }
}

extern "C" void kernel_launch(void* const* d_in, const int* in_sizes, int n_in,
                              void* d_out, int out_size, void* d_ws, size_t ws_size,
                              hipStream_t stream) {
    const float* z_i = (const float*)d_in[0];
    const float* z_j = (const float*)d_in[1];
    float* out = (float*)d_out;

    ushort* znb      = (ushort*)d_ws;                                  // 4 MB
    float*  sim_pos  = (float*)((char*)d_ws + (size_t)TWO_N * D * 2);  // 32 KB
    float*  denom    = sim_pos + TWO_N;                                // 32 KB

    norm_pos_kernel<<<NHALF / 4, 256, 0, stream>>>(z_i, z_j, znb, sim_pos, denom);
    gemm_denom_kernel<<<NPERS, 256, 0, stream>>>(znb, denom);
    final_kernel<<<1, 1024, 0, stream>>>(sim_pos, denom, out);
}

// Round 14
// 49.764 us; speedup vs baseline: 3.8310x; 1.5709x over previous
//
#include <hip/hip_runtime.h>
#include <hip/hip_bf16.h>
#include <hip/hip_fp8.h>

#define TWO_N 8192
#define NHALF 4096
#define D 256
#define NTILE 64            // 8192 / 128 tiles per dimension
#define BLK_BYTES 32768     // bytes per 128-row block: 128 rows * 256 fp8
static constexpr float INV_T = 2.0f; // 1 / 0.5

typedef __attribute__((ext_vector_type(4))) float f32x4;

#define AS1 __attribute__((address_space(1)))
#define AS3 __attribute__((address_space(3)))

// pack 4 floats -> 4 OCP e4m3 bytes
__device__ __forceinline__ unsigned int pack4_e4m3(float a, float b, float c, float d) {
#if __has_builtin(__builtin_amdgcn_cvt_pk_fp8_f32)
    int p = 0;
    p = __builtin_amdgcn_cvt_pk_fp8_f32(a, b, p, false);  // bytes 0,1
    p = __builtin_amdgcn_cvt_pk_fp8_f32(c, d, p, true);   // bytes 2,3
    return (unsigned int)p;
#else
    __hip_fp8_e4m3 qa(a), qb(b), qc(c), qd(d);
    return (unsigned int)qa.__x | ((unsigned int)qb.__x << 8) |
           ((unsigned int)qc.__x << 16) | ((unsigned int)qd.__x << 24);
#endif
}

// ------ kernel 1: fused normalize + positive-pair sim, blocked fp8 out ------
// znb8 layout (bytes): [rowblock(64)][kstep(8)][kgrp(4)][row(128)][e(8)]
//   byte = rb*32768 + (k>>5)*4096 + ((k>>3)&3)*1024 + (row&127)*8 + (k&7)
// Each (tile,K-step) is one contiguous 4 KB region; LDS image of it is the
// conflict-free K-major layout; fragment granule = 8 fp8 = 8 B per lane.
// sim_pos stays EXACT fp32 (computed from raw inputs).
__global__ __launch_bounds__(256) void norm_pos_kernel(
        const float* __restrict__ z_i, const float* __restrict__ z_j,
        unsigned char* __restrict__ znb, float* __restrict__ sim_pos,
        float* __restrict__ denom) {
    const int wid = threadIdx.x >> 6, lane = threadIdx.x & 63;
    const int i = blockIdx.x * 4 + wid;  // 0..4095
    const float4 vi = *reinterpret_cast<const float4*>(z_i + (size_t)i * D + lane * 4);
    const float4 vj = *reinterpret_cast<const float4*>(z_j + (size_t)i * D + lane * 4);
    float ssi = vi.x * vi.x + vi.y * vi.y + vi.z * vi.z + vi.w * vi.w;
    float ssj = vj.x * vj.x + vj.y * vj.y + vj.z * vj.z + vj.w * vj.w;
    float dt  = vi.x * vj.x + vi.y * vj.y + vi.z * vj.z + vi.w * vj.w;
    #pragma unroll
    for (int off = 32; off; off >>= 1) {
        ssi += __shfl_xor(ssi, off);
        ssj += __shfl_xor(ssj, off);
        dt  += __shfl_xor(dt,  off);
    }
    const float ri = rsqrtf(ssi), rj = rsqrtf(ssj);
    const unsigned int pi = pack4_e4m3(vi.x * ri, vi.y * ri, vi.z * ri, vi.w * ri);
    const unsigned int pj = pack4_e4m3(vj.x * rj, vj.y * rj, vj.z * rj, vj.w * rj);
    // lane covers k = lane*4 .. lane*4+3 of its row
    const size_t sub = (size_t)(lane >> 3) * 4096 + (size_t)((lane >> 1) & 3) * 1024
                     + (size_t)(i & 127) * 8 + (lane & 1) * 4;
    const int i2 = i + NHALF;
    *reinterpret_cast<unsigned int*>(znb + (size_t)(i  >> 7) * BLK_BYTES + sub) = pi;
    *reinterpret_cast<unsigned int*>(znb + (size_t)(i2 >> 7) * BLK_BYTES + sub) = pj;
    if (lane == 0) {
        const float sp = dt * ri * rj * INV_T;
        sim_pos[i] = sp;
        sim_pos[i + NHALF] = sp;   // symmetric
        denom[i] = 0.0f;
        denom[i + NHALF] = 0.0f;
    }
}

// ------ kernel 2: fp8 symmetric sim-GEMM + exp + row/col sums ------
// R7-exact structure: BM=BN=128, BK=32, 4 waves (2x2), ring-3 counted-vmcnt,
// 2D grid with block-uniform triangle exit. fp8 halves staged bytes:
// 4 KB/tile/step, 2 global_load_lds per thread per STAGE -> vmcnt(2) gates.
// mfma_f32_16x16x32_fp8_fp8 (C/D layout identical to bf16 -> same epilogue).
__global__ __launch_bounds__(256) void gemm_denom_kernel(
        const unsigned char* __restrict__ znb, float* __restrict__ denom) {
    const int tr = blockIdx.x;
    const int tc = blockIdx.y;
    if (tc < tr) return;  // block-uniform exit before any sync

    __shared__ unsigned char As[3][4096];  // 3 x 4 KB
    __shared__ unsigned char Bs[3][4096];

    const int tid  = threadIdx.x;
    const int lane = tid & 63;
    const int wid  = tid >> 6;
    const int wr   = wid >> 1;
    const int wc   = wid & 1;
    const int r16  = lane & 15;
    const int kgrp = lane >> 4;
    const int row0 = tr * 128;
    const int col0 = tc * 128;

    // staging: thread t covers bytes [t*16, t*16+16) of the 4 KB step region
    const unsigned char* gA = znb + (size_t)tr * BLK_BYTES + tid * 16;
    const unsigned char* gB = znb + (size_t)tc * BLK_BYTES + tid * 16;
    const int dst = wid * 1024;  // wave-uniform LDS dest (bytes); +lane*16 by HW

    #define STAGE(buf, koff)                                                      \
        do {                                                                      \
            __builtin_amdgcn_global_load_lds((const AS1 void*)(gA + (koff)),      \
                (AS3 void*)(As[buf] + dst), 16, 0, 0);                            \
            __builtin_amdgcn_global_load_lds((const AS1 void*)(gB + (koff)),      \
                (AS3 void*)(Bs[buf] + dst), 16, 0, 0);                            \
        } while (0)

    f32x4 acc[4][4];
    #pragma unroll
    for (int m = 0; m < 4; ++m)
        #pragma unroll
        for (int n = 0; n < 4; ++n) {
            f32x4 z = {0.f, 0.f, 0.f, 0.f};
            acc[m][n] = z;
        }

    STAGE(0, 0);
    STAGE(1, 4096);

    #pragma unroll
    for (int ks = 0; ks < 8; ++ks) {
        const int cur = ks % 3;
        // counted wait: stage(ks) landed (2 loads of stage ks+1 may fly) [T4]
        if (ks < 7) asm volatile("s_waitcnt vmcnt(2)" ::: "memory");
        else        asm volatile("s_waitcnt vmcnt(0)" ::: "memory");
        __builtin_amdgcn_s_barrier();
        asm volatile("" ::: "memory");  // pin: no loads migrate above barrier
        if (ks < 6) STAGE((ks + 2) % 3, (ks + 2) * 4096);
        long a[4], b[4];
        #pragma unroll
        for (int m = 0; m < 4; ++m)
            a[m] = *reinterpret_cast<const long*>(
                As[cur] + kgrp * 1024 + (wr * 64 + m * 16 + r16) * 8);
        #pragma unroll
        for (int n = 0; n < 4; ++n)
            b[n] = *reinterpret_cast<const long*>(
                Bs[cur] + kgrp * 1024 + (wc * 64 + n * 16 + r16) * 8);
        #pragma unroll
        for (int m = 0; m < 4; ++m)
            #pragma unroll
            for (int n = 0; n < 4; ++n)
                acc[m][n] = __builtin_amdgcn_mfma_f32_16x16x32_fp8_fp8(
                    a[m], b[n], acc[m][n], 0, 0, 0);
    }
    #undef STAGE

    // ---- epilogue: exp, diag zero, row sums (+ col sums if off-diagonal) ----
    const bool offdiag = (tr != tc);
    float cs[4] = {0.f, 0.f, 0.f, 0.f};
    #pragma unroll
    for (int m = 0; m < 4; ++m) {
        #pragma unroll
        for (int reg = 0; reg < 4; ++reg) {
            const int rg = row0 + wr * 64 + m * 16 + kgrp * 4 + reg;
            float rs = 0.f;
            #pragma unroll
            for (int n = 0; n < 4; ++n) {
                const int cg = col0 + wc * 64 + n * 16 + r16;
                float e = __expf(acc[m][n][reg] * INV_T);
                if (rg == cg) e = 0.f;   // only possible when tr==tc
                rs += e;
                cs[n] += e;
            }
            rs += __shfl_xor(rs, 1);
            rs += __shfl_xor(rs, 2);
            rs += __shfl_xor(rs, 4);
            rs += __shfl_xor(rs, 8);
            if (r16 == 0) atomicAdd(&denom[rg], rs);
        }
    }
    if (offdiag) {
        #pragma unroll
        for (int n = 0; n < 4; ++n) {
            cs[n] += __shfl_xor(cs[n], 16);
            cs[n] += __shfl_xor(cs[n], 32);
        }
        if (kgrp == 0) {
            #pragma unroll
            for (int n = 0; n < 4; ++n)
                atomicAdd(&denom[col0 + wc * 64 + n * 16 + r16], cs[n]);
        }
    }
}

// ---------------- kernel 3: final loss reduction ----------------
__global__ __launch_bounds__(1024) void final_kernel(
        const float* __restrict__ sim_pos, const float* __restrict__ denom,
        float* __restrict__ out) {
    const int tid = threadIdx.x;
    float s = 0.f;
    for (int i = tid; i < TWO_N; i += 1024)
        s += sim_pos[i] - logf(denom[i]);
    #pragma unroll
    for (int off = 32; off; off >>= 1) s += __shfl_down(s, off);
    __shared__ float red[16];
    const int wid = tid >> 6, lane = tid & 63;
    if (lane == 0) red[wid] = s;
    __syncthreads();
    if (tid == 0) {
        float t = 0.f;
        #pragma unroll
        for (int w = 0; w < 16; ++w) t += red[w];
        out[0] = -t / (float)TWO_N;
    }
}

extern "C" void kernel_launch(void* const* d_in, const int* in_sizes, int n_in,
                              void* d_out, int out_size, void* d_ws, size_t ws_size,
                              hipStream_t stream) {
    const float* z_i = (const float*)d_in[0];
    const float* z_j = (const float*)d_in[1];
    float* out = (float*)d_out;

    unsigned char* znb = (unsigned char*)d_ws;                         // 2 MB
    float* sim_pos = (float*)((char*)d_ws + (size_t)TWO_N * D * 2);    // at +4 MB
    float* denom   = sim_pos + TWO_N;

    norm_pos_kernel<<<NHALF / 4, 256, 0, stream>>>(z_i, z_j, znb, sim_pos, denom);
    dim3 grid(NTILE, NTILE);
    gemm_denom_kernel<<<grid, 256, 0, stream>>>(znb, denom);
    final_kernel<<<1, 1024, 0, stream>>>(sim_pos, denom, out);
}

// Round 15
// 47.251 us; speedup vs baseline: 4.0347x; 1.0532x over previous
//
#include <hip/hip_runtime.h>
#include <hip/hip_bf16.h>
#include <hip/hip_fp8.h>

#define TWO_N 8192
#define NHALF 4096
#define D 256
#define NTILE 64            // 8192 / 128 tiles per dimension
#define BLK_BYTES 32768     // bytes per 128-row block: 128 rows * 256 fp8
static constexpr float INV_T = 2.0f; // 1 / 0.5

typedef __attribute__((ext_vector_type(4))) float f32x4;

#define AS1 __attribute__((address_space(1)))
#define AS3 __attribute__((address_space(3)))

// pack 4 floats -> 4 OCP e4m3 bytes
__device__ __forceinline__ unsigned int pack4_e4m3(float a, float b, float c, float d) {
#if __has_builtin(__builtin_amdgcn_cvt_pk_fp8_f32)
    int p = 0;
    p = __builtin_amdgcn_cvt_pk_fp8_f32(a, b, p, false);  // bytes 0,1
    p = __builtin_amdgcn_cvt_pk_fp8_f32(c, d, p, true);   // bytes 2,3
    return (unsigned int)p;
#else
    __hip_fp8_e4m3 qa(a), qb(b), qc(c), qd(d);
    return (unsigned int)qa.__x | ((unsigned int)qb.__x << 8) |
           ((unsigned int)qc.__x << 16) | ((unsigned int)qd.__x << 24);
#endif
}

// ------ kernel 1: fused normalize + positive-pair sim, blocked fp8 out ------
// znb8 layout (bytes): [rowblock(64)][kstep(4)][kchunk(8)][row(128)][e(8)]
//   byte = rb*32768 + (k>>6)*8192 + ((k>>3)&7)*1024 + (row&127)*8 + (k&7)
// Each (tile, BK=64 step) is one contiguous 8 KB region; its LDS image is the
// conflict-free K-major layout. sim_pos stays EXACT fp32. Also zeroes the
// final-reduction accumulator/ticket (graph-replay safe: re-zeroed per call).
__global__ __launch_bounds__(256) void norm_pos_kernel(
        const float* __restrict__ z_i, const float* __restrict__ z_j,
        unsigned char* __restrict__ znb, float* __restrict__ sim_pos,
        float* __restrict__ denom, float* __restrict__ facc,
        int* __restrict__ ftick) {
    const int wid = threadIdx.x >> 6, lane = threadIdx.x & 63;
    const int i = blockIdx.x * 4 + wid;  // 0..4095
    if (blockIdx.x == 0 && threadIdx.x == 0) { facc[0] = 0.0f; ftick[0] = 0; }
    const float4 vi = *reinterpret_cast<const float4*>(z_i + (size_t)i * D + lane * 4);
    const float4 vj = *reinterpret_cast<const float4*>(z_j + (size_t)i * D + lane * 4);
    float ssi = vi.x * vi.x + vi.y * vi.y + vi.z * vi.z + vi.w * vi.w;
    float ssj = vj.x * vj.x + vj.y * vj.y + vj.z * vj.z + vj.w * vj.w;
    float dt  = vi.x * vj.x + vi.y * vj.y + vi.z * vj.z + vi.w * vj.w;
    #pragma unroll
    for (int off = 32; off; off >>= 1) {
        ssi += __shfl_xor(ssi, off);
        ssj += __shfl_xor(ssj, off);
        dt  += __shfl_xor(dt,  off);
    }
    const float ri = rsqrtf(ssi), rj = rsqrtf(ssj);
    const unsigned int pi = pack4_e4m3(vi.x * ri, vi.y * ri, vi.z * ri, vi.w * ri);
    const unsigned int pj = pack4_e4m3(vj.x * rj, vj.y * rj, vj.z * rj, vj.w * rj);
    // lane covers k = lane*4 .. lane*4+3:
    //   kstep = lane>>4, kchunk = (lane>>1)&7, e = (lane&1)*4
    const size_t sub = (size_t)(lane >> 4) * 8192 + (size_t)((lane >> 1) & 7) * 1024
                     + (size_t)(i & 127) * 8 + (lane & 1) * 4;
    const int i2 = i + NHALF;
    *reinterpret_cast<unsigned int*>(znb + (size_t)(i  >> 7) * BLK_BYTES + sub) = pi;
    *reinterpret_cast<unsigned int*>(znb + (size_t)(i2 >> 7) * BLK_BYTES + sub) = pj;
    if (lane == 0) {
        const float sp = dt * ri * rj * INV_T;
        sim_pos[i] = sp;
        sim_pos[i + NHALF] = sp;   // symmetric
        denom[i] = 0.0f;
        denom[i + NHALF] = 0.0f;
    }
}

// ------ kernel 2: fp8 symmetric sim-GEMM, BK=64 (4 convoys/tile) ------
// BM=BN=128, 4 waves (2x2), ring-3 counted-vmcnt, 2D grid + triangle exit.
// Per STAGE: 8 KB A + 8 KB B = 4 global_load_lds/thread -> gates vmcnt(8).
// Per step: 2 K=32 slices x (8 ds_read_b64 + 16 mfma_f32_16x16x32_fp8_fp8).
__global__ __launch_bounds__(256) void gemm_denom_kernel(
        const unsigned char* __restrict__ znb, float* __restrict__ denom) {
    const int tr = blockIdx.x;
    const int tc = blockIdx.y;
    if (tc < tr) return;  // block-uniform exit before any sync

    __shared__ unsigned char As[3][8192];  // 3 x 8 KB
    __shared__ unsigned char Bs[3][8192];

    const int tid  = threadIdx.x;
    const int lane = tid & 63;
    const int wid  = tid >> 6;
    const int wr   = wid >> 1;
    const int wc   = wid & 1;
    const int r16  = lane & 15;
    const int kgrp = lane >> 4;
    const int row0 = tr * 128;
    const int col0 = tc * 128;

    // staging: thread t covers bytes [t*16, t*16+16) of each 4 KB half-region
    const unsigned char* gA = znb + (size_t)tr * BLK_BYTES + tid * 16;
    const unsigned char* gB = znb + (size_t)tc * BLK_BYTES + tid * 16;
    const int dst = wid * 1024;  // wave-uniform LDS dest (bytes); +lane*16 by HW

    #define STAGE(buf, koff)                                                      \
        do {                                                                      \
            __builtin_amdgcn_global_load_lds((const AS1 void*)(gA + (koff)),      \
                (AS3 void*)(As[buf] + dst), 16, 0, 0);                            \
            __builtin_amdgcn_global_load_lds((const AS1 void*)(gA + (koff) + 4096),\
                (AS3 void*)(As[buf] + 4096 + dst), 16, 0, 0);                     \
            __builtin_amdgcn_global_load_lds((const AS1 void*)(gB + (koff)),      \
                (AS3 void*)(Bs[buf] + dst), 16, 0, 0);                            \
            __builtin_amdgcn_global_load_lds((const AS1 void*)(gB + (koff) + 4096),\
                (AS3 void*)(Bs[buf] + 4096 + dst), 16, 0, 0);                     \
        } while (0)

    f32x4 acc[4][4];
    #pragma unroll
    for (int m = 0; m < 4; ++m)
        #pragma unroll
        for (int n = 0; n < 4; ++n) {
            f32x4 z = {0.f, 0.f, 0.f, 0.f};
            acc[m][n] = z;
        }

    STAGE(0, 0);
    STAGE(1, 8192);

    #pragma unroll
    for (int ks = 0; ks < 4; ++ks) {
        const int cur = ks % 3;
        // counted gate: stage(ks) landed; stage(ks+1)'s 8 loads may fly [T4]
        if (ks < 3) asm volatile("s_waitcnt vmcnt(8)" ::: "memory");
        else        asm volatile("s_waitcnt vmcnt(0)" ::: "memory");
        __builtin_amdgcn_s_barrier();
        asm volatile("" ::: "memory");  // pin: no loads migrate above barrier
        if (ks < 2) STAGE((ks + 2) % 3, (ks + 2) * 8192);
        #pragma unroll
        for (int s = 0; s < 2; ++s) {   // two K=32 slices within BK=64
            long a[4], b[4];
            #pragma unroll
            for (int m = 0; m < 4; ++m)
                a[m] = *reinterpret_cast<const long*>(
                    As[cur] + (((s * 4 + kgrp) * 128) + wr * 64 + m * 16 + r16) * 8);
            #pragma unroll
            for (int n = 0; n < 4; ++n)
                b[n] = *reinterpret_cast<const long*>(
                    Bs[cur] + (((s * 4 + kgrp) * 128) + wc * 64 + n * 16 + r16) * 8);
            #pragma unroll
            for (int m = 0; m < 4; ++m)
                #pragma unroll
                for (int n = 0; n < 4; ++n)
                    acc[m][n] = __builtin_amdgcn_mfma_f32_16x16x32_fp8_fp8(
                        a[m], b[n], acc[m][n], 0, 0, 0);
        }
    }
    #undef STAGE

    // ---- epilogue: exp, diag zero, row sums (+ col sums if off-diagonal) ----
    const bool offdiag = (tr != tc);
    float cs[4] = {0.f, 0.f, 0.f, 0.f};
    #pragma unroll
    for (int m = 0; m < 4; ++m) {
        #pragma unroll
        for (int reg = 0; reg < 4; ++reg) {
            const int rg = row0 + wr * 64 + m * 16 + kgrp * 4 + reg;
            float rs = 0.f;
            #pragma unroll
            for (int n = 0; n < 4; ++n) {
                const int cg = col0 + wc * 64 + n * 16 + r16;
                float e = __expf(acc[m][n][reg] * INV_T);
                if (rg == cg) e = 0.f;   // only possible when tr==tc
                rs += e;
                cs[n] += e;
            }
            rs += __shfl_xor(rs, 1);
            rs += __shfl_xor(rs, 2);
            rs += __shfl_xor(rs, 4);
            rs += __shfl_xor(rs, 8);
            if (r16 == 0) atomicAdd(&denom[rg], rs);
        }
    }
    if (offdiag) {
        #pragma unroll
        for (int n = 0; n < 4; ++n) {
            cs[n] += __shfl_xor(cs[n], 16);
            cs[n] += __shfl_xor(cs[n], 32);
        }
        if (kgrp == 0) {
            #pragma unroll
            for (int n = 0; n < 4; ++n)
                atomicAdd(&denom[col0 + wc * 64 + n * 16 + r16], cs[n]);
        }
    }
}

// ------ kernel 3: parallel final loss reduction (8 blocks + ticket) ------
__global__ __launch_bounds__(1024) void final_kernel(
        const float* __restrict__ sim_pos, const float* __restrict__ denom,
        float* __restrict__ facc, int* __restrict__ ftick,
        float* __restrict__ out) {
    const int tid = threadIdx.x;
    const int gid = blockIdx.x * 1024 + tid;
    float s = sim_pos[gid] - __logf(denom[gid]);
    #pragma unroll
    for (int off = 32; off; off >>= 1) s += __shfl_down(s, off);
    __shared__ float red[16];
    const int wid = tid >> 6, lane = tid & 63;
    if (lane == 0) red[wid] = s;
    __syncthreads();
    if (tid == 0) {
        float bs = 0.f;
        #pragma unroll
        for (int w = 0; w < 16; ++w) bs += red[w];
        atomicAdd(facc, bs);
        __threadfence();
        const int t = atomicAdd(ftick, 1);
        if (t == 7) {
            const float tot = atomicAdd(facc, 0.0f);  // atomic read: final sum
            out[0] = -tot / (float)TWO_N;
        }
    }
}

extern "C" void kernel_launch(void* const* d_in, const int* in_sizes, int n_in,
                              void* d_out, int out_size, void* d_ws, size_t ws_size,
                              hipStream_t stream) {
    const float* z_i = (const float*)d_in[0];
    const float* z_j = (const float*)d_in[1];
    float* out = (float*)d_out;

    unsigned char* znb = (unsigned char*)d_ws;                         // 2 MB
    float* sim_pos = (float*)((char*)d_ws + (size_t)TWO_N * D * 2);    // at +4 MB
    float* denom   = sim_pos + TWO_N;
    float* facc    = denom + TWO_N;
    int*   ftick   = (int*)(facc + 1);

    norm_pos_kernel<<<NHALF / 4, 256, 0, stream>>>(z_i, z_j, znb, sim_pos, denom,
                                                   facc, ftick);
    dim3 grid(NTILE, NTILE);
    gemm_denom_kernel<<<grid, 256, 0, stream>>>(znb, denom);
    final_kernel<<<TWO_N / 1024, 1024, 0, stream>>>(sim_pos, denom, facc, ftick, out);
}